// Round 2
// baseline (70.108 us; speedup 1.0000x reference)
//
#include <hip/hip_runtime.h>

#define N_TOKS 1024
#define N_ATOMS 4096
#define CS 384
#define CZ 128
#define CATOM 128
#define CPAIR 16
#define NQ 32
#define NK 128
#define NBLK 128          // N_ATOMS / NQ
#define KOFF (-48)        // NQ/2 - NK/2
#define KSEG 32
#define QH 16             // q-half per k_z block
#define LN_EPS 1e-5f

// ============ k1: blocks 0..127 -> s = LN(si)@W_s+b_s (8 tokens/block);
// ============     block 128     -> tok[] cumsum + searchsorted ============
__global__ __launch_bounds__(256) void k1(const int* __restrict__ na, int* __restrict__ tok,
                                          const float* __restrict__ si, const float* __restrict__ lnw,
                                          const float* __restrict__ Ws, const float* __restrict__ bs,
                                          const float* __restrict__ mask, float* __restrict__ s_out) {
    int t = threadIdx.x;
    if (blockIdx.x == 128) {
        // ---- tok part ----
        __shared__ int ends[N_TOKS];
        __shared__ int ps[256];
        int4 v = ((const int4*)na)[t];
        int e0 = v.x, e1 = e0 + v.y, e2 = e1 + v.z, e3 = e2 + v.w;
        ps[t] = e3;
        __syncthreads();
        for (int off = 1; off < 256; off <<= 1) {
            int u = (t >= off) ? ps[t - off] : 0;
            __syncthreads();
            ps[t] += u;
            __syncthreads();
        }
        int base = (t > 0) ? ps[t - 1] : 0;
        ends[4 * t + 0] = base + e0;
        ends[4 * t + 1] = base + e1;
        ends[4 * t + 2] = base + e2;
        ends[4 * t + 3] = base + e3;
        __syncthreads();
        #pragma unroll
        for (int i = 0; i < 16; i++) {
            int a = t + i * 256;
            int lo = 0, hi = N_TOKS - 1;
            while (lo < hi) {
                int mid = (lo + hi) >> 1;
                if (ends[mid] > a) hi = mid; else lo = mid + 1;
            }
            tok[a] = lo;
        }
        return;
    }
    // ---- s part: 8 tokens per block ----
    __shared__ float xh[8][CS];
    int tl = t >> 5, l = t & 31;
    int token = blockIdx.x * 8 + tl;
    {
        const float4* row4 = (const float4*)(si + (size_t)token * CS);
        float4 v[3];
        float sum = 0.f, sq = 0.f;
        #pragma unroll
        for (int i = 0; i < 3; i++) {
            v[i] = row4[l + 32 * i];
            sum += v[i].x + v[i].y + v[i].z + v[i].w;
            sq  += v[i].x * v[i].x + v[i].y * v[i].y + v[i].z * v[i].z + v[i].w * v[i].w;
        }
        #pragma unroll
        for (int m = 16; m >= 1; m >>= 1) { sum += __shfl_xor(sum, m); sq += __shfl_xor(sq, m); }
        float mu = sum * (1.f / CS);
        float rstd = rsqrtf(sq * (1.f / CS) - mu * mu + LN_EPS);
        #pragma unroll
        for (int i = 0; i < 3; i++) {
            int f4i = l + 32 * i;
            float4 g = ((const float4*)lnw)[f4i];
            int cb = f4i * 4;
            xh[tl][cb + 0] = (v[i].x - mu) * rstd * g.x;
            xh[tl][cb + 1] = (v[i].y - mu) * rstd * g.y;
            xh[tl][cb + 2] = (v[i].z - mu) * rstd * g.z;
            xh[tl][cb + 3] = (v[i].w - mu) * rstd * g.w;
        }
    }
    __syncthreads();
    // matvec: thread = (token tl, d4 = t&31); 4 d's per thread, 16 fma per 16B W load
    int d4 = t & 31;
    float4 acc = ((const float4*)bs)[d4];
    const float4* Ws4 = (const float4*)Ws;
    #pragma unroll 4
    for (int c = 0; c < CS; c++) {
        float xv = xh[tl][c];
        float4 w = Ws4[c * 32 + d4];
        acc.x += xv * w.x; acc.y += xv * w.y; acc.z += xv * w.z; acc.w += xv * w.w;
    }
    float m = mask[token];
    acc.x *= m; acc.y *= m; acc.z *= m; acc.w *= m;
    ((float4*)s_out)[(size_t)token * 32 + d4] = acc;
}

// ============ k_z: z at unique token pairs (8 lanes/pair) + plm stream ============
__global__ __launch_bounds__(256) void k_z(const float* __restrict__ zij, const float* __restrict__ lnzw,
                                           const float* __restrict__ Wz, const float* __restrict__ bz,
                                           const int* __restrict__ tok, const float* __restrict__ plm,
                                           float* __restrict__ plm_out) {
    __shared__ float ztile[QH * KSEG * CPAIR];   // 32 KB
    __shared__ float wz_l[CZ * CPAIR];           // 8 KB, XOR-swizzled f4 slots
    __shared__ int tokq[QH], tokk[KSEG];
    __shared__ int qmap[QH], kmap[KSEG];
    __shared__ int uqtok[QH], uktok[KSEG];
    __shared__ float kvalid[KSEG];
    __shared__ int s_uq, s_uk;

    int t = threadIdx.x;
    int x = blockIdx.x;
    int blk32 = x >> 1, half = x & 1;
    int kseg = blockIdx.y;

    // stage Wz into LDS, swizzled: slot(c, d4) = c*16 + (d4 ^ ((c>>4)&3))*4
    for (int i = t; i < CZ * CPAIR / 4; i += 256) {
        int c = i >> 2, d4 = i & 3;
        float4 w = ((const float4*)Wz)[i];
        *(float4*)&wz_l[c * 16 + (d4 ^ ((c >> 4) & 3)) * 4] = w;
    }
    if (t < QH) {
        tokq[t] = tok[blk32 * NQ + half * QH + t];
    } else if (t < QH + KSEG) {
        int kk = t - QH;
        int kg = blk32 * NQ + KOFF + kseg * KSEG + kk;
        kvalid[kk] = (kg >= 0 && kg < N_ATOMS) ? 1.0f : 0.0f;
        tokk[kk] = tok[min(max(kg, 0), N_ATOMS - 1)];
    }
    __syncthreads();
    if (t == 0) {
        int u = 0;
        for (int q = 0; q < QH; q++) { if (q == 0 || tokq[q] != tokq[q - 1]) uqtok[u++] = tokq[q]; qmap[q] = u - 1; }
        s_uq = u;
    } else if (t == 64) {
        int u = 0;
        for (int k = 0; k < KSEG; k++) { if (k == 0 || tokk[k] != tokk[k - 1]) uktok[u++] = tokk[k]; kmap[k] = u - 1; }
        s_uk = u;
    }
    __syncthreads();
    int uq = s_uq, uk = s_uk;
    int npairs = uq * uk;          // typical ~36, worst 512

    int sl = t & 7;                // 8 lanes per pair, lane covers channels [sl*16, sl*16+16)
    int swz = sl & 3;              // = (c>>4)&3 for c in this lane's range
    float lnr[16], bzr[16];
    {
        const float4* l4 = (const float4*)lnzw;
        const float4* b4 = (const float4*)bz;
        #pragma unroll
        for (int i = 0; i < 4; i++) {
            float4 g = l4[sl * 4 + i];
            lnr[4*i+0] = g.x; lnr[4*i+1] = g.y; lnr[4*i+2] = g.z; lnr[4*i+3] = g.w;
            float4 b = b4[i];
            bzr[4*i+0] = b.x; bzr[4*i+1] = b.y; bzr[4*i+2] = b.z; bzr[4*i+3] = b.w;
        }
    }

    for (int p = t >> 3; p < npairs; p += 32) {
        int qi = p / uk, ki = p - qi * uk;
        const float4* rowp = (const float4*)(zij + ((size_t)uqtok[qi] * N_TOKS + uktok[ki]) * CZ + sl * 16);
        float4 r[4];
        float sum = 0.f, sq = 0.f;
        #pragma unroll
        for (int i = 0; i < 4; i++) {
            r[i] = rowp[i];
            sum += r[i].x + r[i].y + r[i].z + r[i].w;
            sq  += r[i].x * r[i].x + r[i].y * r[i].y + r[i].z * r[i].z + r[i].w * r[i].w;
        }
        #pragma unroll
        for (int m = 1; m < 8; m <<= 1) { sum += __shfl_xor(sum, m); sq += __shfl_xor(sq, m); }
        float mu = sum * (1.f / CZ);
        float rstd = rsqrtf(sq * (1.f / CZ) - mu * mu + LN_EPS);
        float xs[16];
        #pragma unroll
        for (int i = 0; i < 4; i++) {
            xs[4*i+0] = r[i].x; xs[4*i+1] = r[i].y; xs[4*i+2] = r[i].z; xs[4*i+3] = r[i].w;
        }
        float acc[16];
        #pragma unroll
        for (int d = 0; d < 16; d++) acc[d] = 0.f;
        #pragma unroll
        for (int j = 0; j < 16; j++) {
            float xv = (xs[j] - mu) * rstd * lnr[j];
            const float* wb = &wz_l[(sl * 16 + j) * 16];
            #pragma unroll
            for (int d4i = 0; d4i < 4; d4i++) {
                float4 w = *(const float4*)&wb[(d4i ^ swz) * 4];
                acc[d4i*4+0] += xv * w.x; acc[d4i*4+1] += xv * w.y;
                acc[d4i*4+2] += xv * w.z; acc[d4i*4+3] += xv * w.w;
            }
        }
        #pragma unroll
        for (int m = 1; m < 8; m <<= 1) {
            #pragma unroll
            for (int d = 0; d < 16; d++) acc[d] += __shfl_xor(acc[d], m);
        }
        if (sl == 0) {
            float* zt = &ztile[(qi * KSEG + ki) * CPAIR];
            #pragma unroll
            for (int i = 0; i < 4; i++) {
                float4 o;
                o.x = acc[4*i+0] + bzr[4*i+0]; o.y = acc[4*i+1] + bzr[4*i+1];
                o.z = acc[4*i+2] + bzr[4*i+2]; o.w = acc[4*i+3] + bzr[4*i+3];
                *(float4*)&zt[4*i] = o;
            }
        }
    }
    __syncthreads();

    // streaming: 16 q * 32 k * 16 d = 2048 float4 per block
    const float4* plm4 = (const float4*)plm;
    float4* out4 = (float4*)plm_out;
    #pragma unroll
    for (int i = 0; i < 8; i++) {
        int f = t + i * 256;
        int d4 = f & 3;
        int kk = (f >> 2) & 31;
        int ql = f >> 7;
        size_t g = ((size_t)(blk32 * NQ + half * QH + ql) * NK + (size_t)kseg * KSEG + kk) * (CPAIR / 4) + d4;
        float4 v = plm4[g];
        float vd = kvalid[kk];
        const float4 z = *(const float4*)&ztile[(qmap[ql] * KSEG + kmap[kk]) * CPAIR + d4 * 4];
        v.x += vd * z.x; v.y += vd * z.y; v.z += vd * z.z; v.w += vd * z.w;
        out4[g] = v;
    }
}

// ============ cl_out = cl + s[tok];  ql = cl_out + rl@W_r + b_r ============
__global__ __launch_bounds__(256) void k_cq(const float* __restrict__ cl, const float* __restrict__ rl,
                                            const float* __restrict__ Wr, const float* __restrict__ br,
                                            const float* __restrict__ s, const int* __restrict__ tok,
                                            float* __restrict__ cl_out, float* __restrict__ ql) {
    int t = blockIdx.x * 256 + threadIdx.x;   // over N_ATOMS * 32 float4s
    int a = t >> 5, d4 = t & 31;
    int tk = tok[a];
    float4 c  = ((const float4*)cl)[t];
    float4 sv = ((const float4*)s)[(size_t)tk * 32 + d4];
    float4 co; co.x = c.x + sv.x; co.y = c.y + sv.y; co.z = c.z + sv.z; co.w = c.w + sv.w;
    float x = rl[a * 3 + 0], y = rl[a * 3 + 1], z = rl[a * 3 + 2];
    float4 w0 = ((const float4*)Wr)[d4];
    float4 w1 = ((const float4*)Wr)[32 + d4];
    float4 w2 = ((const float4*)Wr)[64 + d4];
    float4 bb = ((const float4*)br)[d4];
    float4 q;
    q.x = co.x + x * w0.x + y * w1.x + z * w2.x + bb.x;
    q.y = co.y + x * w0.y + y * w1.y + z * w2.y + bb.y;
    q.z = co.z + x * w0.z + y * w1.z + z * w2.z + bb.z;
    q.w = co.w + x * w0.w + y * w1.w + z * w2.w + bb.w;
    ((float4*)cl_out)[t] = co;
    ((float4*)ql)[t] = q;
}

extern "C" void kernel_launch(void* const* d_in, const int* in_sizes, int n_in,
                              void* d_out, int out_size, void* d_ws, size_t ws_size,
                              hipStream_t stream) {
    (void)in_sizes; (void)n_in; (void)out_size; (void)ws_size;
    const float* token_mask = (const float*)d_in[0];
    const int*   num_atoms  = (const int*)d_in[1];
    const float* cl   = (const float*)d_in[2];
    const float* plm  = (const float*)d_in[3];
    const float* si   = (const float*)d_in[4];
    const float* zij  = (const float*)d_in[5];
    const float* rl   = (const float*)d_in[6];
    const float* ln_s_w = (const float*)d_in[7];
    const float* W_s  = (const float*)d_in[8];
    const float* b_s  = (const float*)d_in[9];
    const float* ln_z_w = (const float*)d_in[10];
    const float* W_z  = (const float*)d_in[11];
    const float* b_z  = (const float*)d_in[12];
    const float* W_r  = (const float*)d_in[13];
    const float* b_r  = (const float*)d_in[14];

    float* out_cl  = (float*)d_out;
    float* out_plm = out_cl + (size_t)N_ATOMS * CATOM;
    float* out_ql  = out_plm + (size_t)NBLK * NQ * NK * CPAIR;

    int*   tok_ws = (int*)d_ws;
    float* s_ws   = (float*)((char*)d_ws + N_ATOMS * sizeof(int));

    k1<<<129, 256, 0, stream>>>(num_atoms, tok_ws, si, ln_s_w, W_s, b_s, token_mask, s_ws);
    k_z<<<dim3(NBLK * 2, NK / KSEG), 256, 0, stream>>>(zij, ln_z_w, W_z, b_z, tok_ws, plm, out_plm);
    k_cq<<<(N_ATOMS * 32) / 256, 256, 0, stream>>>(cl, rl, W_r, b_r, s_ws, tok_ws, out_cl, out_ql);
}

// Round 3
// 46.434 us; speedup vs baseline: 1.5098x; 1.5098x over previous
//
#include <hip/hip_runtime.h>

#define N_TOKS 1024
#define N_ATOMS 4096
#define CS 384
#define CZ 128
#define CATOM 128
#define CPAIR 16
#define NQ 32
#define NK 128
#define NBLK 128          // N_ATOMS / NQ
#define KOFF (-48)        // NQ/2 - NK/2
#define KSEG 32
#define LN_EPS 1e-5f

// ================= kA: 256 blocks, 4 tokens each =================
// per block: scan(num_atoms) -> ends[]; LN(si)+matvec -> s in LDS;
// then cl_out = cl + s[tok], ql = cl_out + rl@W_r + b_r for exactly this
// block's atoms (atom range from the scan; s never goes to HBM).
__global__ __launch_bounds__(256) void kA(const int* __restrict__ na, const float* __restrict__ si,
                                          const float* __restrict__ lnw, const float* __restrict__ Ws,
                                          const float* __restrict__ bs, const float* __restrict__ mask,
                                          const float* __restrict__ cl, const float* __restrict__ rl,
                                          const float* __restrict__ Wr, const float* __restrict__ br,
                                          float* __restrict__ cl_out, float* __restrict__ ql) {
    __shared__ int ends[N_TOKS];
    __shared__ int ps[256];
    __shared__ float xh[CS][4];          // LN'd si, [channel][local token]
    __shared__ float sacc[8][4][CATOM];  // partial matvec, [c-chunk][token][d]
    __shared__ float s_l[4][CATOM];
    int t = threadIdx.x, b = blockIdx.x, Tlo = b * 4;

    // ---- scan ----
    {
        int4 v = ((const int4*)na)[t];
        int e0 = v.x, e1 = e0 + v.y, e2 = e1 + v.z, e3 = e2 + v.w;
        ps[t] = e3;
        __syncthreads();
        for (int off = 1; off < 256; off <<= 1) {
            int u = (t >= off) ? ps[t - off] : 0;
            __syncthreads();
            ps[t] += u;
            __syncthreads();
        }
        int base = (t > 0) ? ps[t - 1] : 0;
        ends[4 * t + 0] = base + e0;
        ends[4 * t + 1] = base + e1;
        ends[4 * t + 2] = base + e2;
        ends[4 * t + 3] = base + e3;
    }

    // ---- LN: 64 lanes per token ----
    {
        int tl = t >> 6, l = t & 63;
        const float4* row4 = (const float4*)(si + (size_t)(Tlo + tl) * CS);
        float4 v0 = row4[l];
        float4 v1 = make_float4(0.f, 0.f, 0.f, 0.f);
        if (l < 32) v1 = row4[64 + l];
        float sum = v0.x + v0.y + v0.z + v0.w + v1.x + v1.y + v1.z + v1.w;
        float sq = v0.x*v0.x + v0.y*v0.y + v0.z*v0.z + v0.w*v0.w
                 + v1.x*v1.x + v1.y*v1.y + v1.z*v1.z + v1.w*v1.w;
        #pragma unroll
        for (int m = 32; m >= 1; m >>= 1) { sum += __shfl_xor(sum, m); sq += __shfl_xor(sq, m); }
        float mu = sum * (1.f / CS);
        float rstd = rsqrtf(sq * (1.f / CS) - mu * mu + LN_EPS);
        float4 g0 = ((const float4*)lnw)[l];
        xh[4*l+0][tl] = (v0.x - mu) * rstd * g0.x;
        xh[4*l+1][tl] = (v0.y - mu) * rstd * g0.y;
        xh[4*l+2][tl] = (v0.z - mu) * rstd * g0.z;
        xh[4*l+3][tl] = (v0.w - mu) * rstd * g0.w;
        if (l < 32) {
            float4 g1 = ((const float4*)lnw)[64 + l];
            xh[256+4*l+0][tl] = (v1.x - mu) * rstd * g1.x;
            xh[256+4*l+1][tl] = (v1.y - mu) * rstd * g1.y;
            xh[256+4*l+2][tl] = (v1.z - mu) * rstd * g1.z;
            xh[256+4*l+3][tl] = (v1.w - mu) * rstd * g1.w;
        }
    }
    __syncthreads();

    // ---- matvec, c-split: thread = (cc = t>>5, d4 = t&31), each Ws element loaded once/block ----
    {
        int d4 = t & 31, cc = t >> 5;
        float4 a0 = make_float4(0,0,0,0), a1 = a0, a2 = a0, a3 = a0;
        const float4* Ws4 = (const float4*)Ws;
        int c0 = 48 * cc;
        #pragma unroll 4
        for (int c = c0; c < c0 + 48; c++) {
            float4 w = Ws4[(size_t)c * 32 + d4];
            float4 xv = *(const float4*)&xh[c][0];
            a0.x += xv.x * w.x; a0.y += xv.x * w.y; a0.z += xv.x * w.z; a0.w += xv.x * w.w;
            a1.x += xv.y * w.x; a1.y += xv.y * w.y; a1.z += xv.y * w.z; a1.w += xv.y * w.w;
            a2.x += xv.z * w.x; a2.y += xv.z * w.y; a2.z += xv.z * w.z; a2.w += xv.z * w.w;
            a3.x += xv.w * w.x; a3.y += xv.w * w.y; a3.z += xv.w * w.z; a3.w += xv.w * w.w;
        }
        *(float4*)&sacc[cc][0][d4 * 4] = a0;
        *(float4*)&sacc[cc][1][d4 * 4] = a1;
        *(float4*)&sacc[cc][2][d4 * 4] = a2;
        *(float4*)&sacc[cc][3][d4 * 4] = a3;
    }
    __syncthreads();
    if (t < 128) {
        int tk = t >> 5, d = t & 31;
        float4 a = make_float4(0,0,0,0);
        #pragma unroll
        for (int cc = 0; cc < 8; cc++) {
            float4 p = *(const float4*)&sacc[cc][tk][d * 4];
            a.x += p.x; a.y += p.y; a.z += p.z; a.w += p.w;
        }
        float4 bb = ((const float4*)bs)[d];
        float m = mask[Tlo + tk];
        a.x = (a.x + bb.x) * m; a.y = (a.y + bb.y) * m;
        a.z = (a.z + bb.z) * m; a.w = (a.w + bb.w) * m;
        *(float4*)&s_l[tk][d * 4] = a;
    }
    __syncthreads();

    // ---- atom phase: this block's atom range ----
    int elo = (Tlo == 0) ? 0 : ends[Tlo - 1];
    int e_0 = ends[Tlo], e_1 = ends[Tlo + 1], e_2 = ends[Tlo + 2];
    int ehi = (b == 255) ? N_ATOMS : ends[Tlo + 3];
    elo = min(max(elo, 0), N_ATOMS);
    ehi = min(max(ehi, 0), N_ATOMS);
    if (ehi < elo) ehi = elo;
    int items = (ehi - elo) * 32;
    for (int i = t; i < items; i += 256) {
        int a = elo + (i >> 5), d = i & 31;
        int tk = (a >= e_0) + (a >= e_1) + (a >= e_2);
        float4 c4 = ((const float4*)cl)[(size_t)a * 32 + d];
        float4 sv = *(const float4*)&s_l[tk][d * 4];
        float4 co;
        co.x = c4.x + sv.x; co.y = c4.y + sv.y; co.z = c4.z + sv.z; co.w = c4.w + sv.w;
        float x = rl[a * 3 + 0], y = rl[a * 3 + 1], z = rl[a * 3 + 2];
        float4 w0 = ((const float4*)Wr)[d];
        float4 w1 = ((const float4*)Wr)[32 + d];
        float4 w2 = ((const float4*)Wr)[64 + d];
        float4 bb = ((const float4*)br)[d];
        float4 q;
        q.x = co.x + x * w0.x + y * w1.x + z * w2.x + bb.x;
        q.y = co.y + x * w0.y + y * w1.y + z * w2.y + bb.y;
        q.z = co.z + x * w0.z + y * w1.z + z * w2.z + bb.z;
        q.w = co.w + x * w0.w + y * w1.w + z * w2.w + bb.w;
        ((float4*)cl_out)[(size_t)a * 32 + d] = co;
        ((float4*)ql)[(size_t)a * 32 + d] = q;
    }
}

// ================= kB: z at gathered token pairs + plm stream (R0 inner loops) =================
__global__ __launch_bounds__(256) void kB(const int* __restrict__ na, const float* __restrict__ zij,
                                          const float* __restrict__ lnzw, const float* __restrict__ Wz,
                                          const float* __restrict__ bz, const float* __restrict__ plm,
                                          float* __restrict__ plm_out) {
    __shared__ float ztile[NQ * KSEG * CPAIR];   // 64 KB
    __shared__ int ends[N_TOKS];
    __shared__ int ps[256];
    __shared__ int tokq[NQ], tokk[KSEG];
    __shared__ int qmap[NQ], kmap[KSEG];
    __shared__ int uqtok[NQ], uktok[KSEG];
    __shared__ float kvalid[KSEG];
    __shared__ int s_uq, s_uk;

    int t = threadIdx.x;
    int blk = blockIdx.x, kseg = blockIdx.y;

    // ---- scan (self-sufficient tok) ----
    {
        int4 v = ((const int4*)na)[t];
        int e0 = v.x, e1 = e0 + v.y, e2 = e1 + v.z, e3 = e2 + v.w;
        ps[t] = e3;
        __syncthreads();
        for (int off = 1; off < 256; off <<= 1) {
            int u = (t >= off) ? ps[t - off] : 0;
            __syncthreads();
            ps[t] += u;
            __syncthreads();
        }
        int base = (t > 0) ? ps[t - 1] : 0;
        ends[4 * t + 0] = base + e0;
        ends[4 * t + 1] = base + e1;
        ends[4 * t + 2] = base + e2;
        ends[4 * t + 3] = base + e3;
    }
    __syncthreads();

    // ---- tok for this block's q-atoms and k-segment ----
    if (t < NQ) {
        int a = blk * NQ + t;
        int lo = 0, hi = N_TOKS - 1;
        while (lo < hi) { int mid = (lo + hi) >> 1; if (ends[mid] > a) hi = mid; else lo = mid + 1; }
        tokq[t] = lo;
    } else if (t >= 64 && t < 64 + KSEG) {
        int kk = t - 64;
        int kg = blk * NQ + KOFF + kseg * KSEG + kk;
        kvalid[kk] = (kg >= 0 && kg < N_ATOMS) ? 1.0f : 0.0f;
        int a = min(max(kg, 0), N_ATOMS - 1);
        int lo = 0, hi = N_TOKS - 1;
        while (lo < hi) { int mid = (lo + hi) >> 1; if (ends[mid] > a) hi = mid; else lo = mid + 1; }
        tokk[kk] = lo;
    }
    __syncthreads();
    if (t == 0) {
        int u = 0;
        for (int q = 0; q < NQ; q++) { if (q == 0 || tokq[q] != tokq[q - 1]) uqtok[u++] = tokq[q]; qmap[q] = u - 1; }
        s_uq = u;
    } else if (t == 64) {
        int u = 0;
        for (int k = 0; k < KSEG; k++) { if (k == 0 || tokk[k] != tokk[k - 1]) uktok[u++] = tokk[k]; kmap[k] = u - 1; }
        s_uk = u;
    }
    __syncthreads();
    int uq = s_uq, uk = s_uk;
    int npairs = uq * uk;   // typical ~72

    // ---- phase 1: z at unique pairs, 1 lane per pair (R0-proven) ----
    for (int p = t; p < npairs; p += 256) {
        int qi = p / uk, ki = p - qi * uk;
        int tq = uqtok[qi], tk = uktok[ki];
        const float* row = zij + ((size_t)tq * N_TOKS + tk) * CZ;
        float sum = 0.f, sq = 0.f;
        for (int c4 = 0; c4 < CZ / 4; c4++) {
            float4 v = *(const float4*)(row + c4 * 4);
            sum += v.x + v.y + v.z + v.w;
            sq  += v.x * v.x + v.y * v.y + v.z * v.z + v.w * v.w;
        }
        float mu = sum * (1.f / CZ);
        float rstd = rsqrtf(sq * (1.f / CZ) - mu * mu + LN_EPS);
        float acc[CPAIR];
        #pragma unroll
        for (int d = 0; d < CPAIR; d++) acc[d] = bz[d];
        for (int c4 = 0; c4 < CZ / 4; c4++) {
            float4 v = *(const float4*)(row + c4 * 4);
            float xs[4] = {v.x, v.y, v.z, v.w};
            #pragma unroll
            for (int j = 0; j < 4; j++) {
                int c = c4 * 4 + j;
                float x = (xs[j] - mu) * rstd * lnzw[c];
                const float* wrow = Wz + c * CPAIR;
                #pragma unroll
                for (int d = 0; d < CPAIR; d++) acc[d] += x * wrow[d];
            }
        }
        float* zt = &ztile[(qi * KSEG + ki) * CPAIR];
        #pragma unroll
        for (int d = 0; d < CPAIR; d++) zt[d] = acc[d];
    }
    __syncthreads();

    // ---- phase 2: stream plm (R0-proven) ----
    const float4* plm4 = (const float4*)plm;
    float4* out4 = (float4*)plm_out;
    #pragma unroll
    for (int i = 0; i < 16; i++) {
        int f = t + i * 256;          // 0..4095
        int d4 = f & 3;
        int kk = (f >> 2) & 31;
        int q  = f >> 7;
        size_t g = (((size_t)(blk * NQ + q) * NK) + (size_t)kseg * KSEG + kk) * (CPAIR / 4) + d4;
        float4 v = plm4[g];
        float vd = kvalid[kk];
        const float4 z = *(const float4*)&ztile[(qmap[q] * KSEG + kmap[kk]) * CPAIR + d4 * 4];
        v.x += vd * z.x; v.y += vd * z.y; v.z += vd * z.z; v.w += vd * z.w;
        out4[g] = v;
    }
}

extern "C" void kernel_launch(void* const* d_in, const int* in_sizes, int n_in,
                              void* d_out, int out_size, void* d_ws, size_t ws_size,
                              hipStream_t stream) {
    (void)in_sizes; (void)n_in; (void)out_size; (void)d_ws; (void)ws_size;
    const float* token_mask = (const float*)d_in[0];
    const int*   num_atoms  = (const int*)d_in[1];
    const float* cl   = (const float*)d_in[2];
    const float* plm  = (const float*)d_in[3];
    const float* si   = (const float*)d_in[4];
    const float* zij  = (const float*)d_in[5];
    const float* rl   = (const float*)d_in[6];
    const float* ln_s_w = (const float*)d_in[7];
    const float* W_s  = (const float*)d_in[8];
    const float* b_s  = (const float*)d_in[9];
    const float* ln_z_w = (const float*)d_in[10];
    const float* W_z  = (const float*)d_in[11];
    const float* b_z  = (const float*)d_in[12];
    const float* W_r  = (const float*)d_in[13];
    const float* b_r  = (const float*)d_in[14];

    float* out_cl  = (float*)d_out;
    float* out_plm = out_cl + (size_t)N_ATOMS * CATOM;
    float* out_ql  = out_plm + (size_t)NBLK * NQ * NK * CPAIR;

    kA<<<256, 256, 0, stream>>>(num_atoms, si, ln_s_w, W_s, b_s, token_mask,
                                cl, rl, W_r, b_r, out_cl, out_ql);
    kB<<<dim3(NBLK, NK / KSEG), 256, 0, stream>>>(num_atoms, zij, ln_z_w, W_z, b_z, plm, out_plm);
}